// Round 7
// baseline (7100.294 us; speedup 1.0000x reference)
//
#include <hip/hip_runtime.h>
#include <stdint.h>

typedef short short8 __attribute__((ext_vector_type(8)));
typedef float float4v __attribute__((ext_vector_type(4)));
typedef uint32_t u32;
typedef uint64_t u64;

#define NSTEPS 512

struct U64x2 { u64 x, y; };

__device__ __forceinline__ unsigned short f2bf(float f) {
  unsigned u = __builtin_bit_cast(unsigned, f);
  u += 0x7fffu + ((u >> 16) & 1u);
  return (unsigned short)(u >> 16);
}

// xbf layout (A-fragment swizzled): short8[ ((l*4+g)*16 + kk)*64 + lane ]
// element (l, g, m, k):  m = lane&15, k = kk*32 + (lane>>4)*8 + j
__global__ __launch_bounds__(256) void xprep_kernel(const float* __restrict__ x,
                                                    short* __restrict__ xbf) {
  unsigned tid = blockIdx.x * 256u + threadIdx.x;   // 2,097,152 total
  unsigned lane = tid & 63u;
  unsigned kk   = (tid >> 6) & 15u;
  unsigned g    = (tid >> 10) & 3u;
  unsigned l    = tid >> 12;
  unsigned m = lane & 15u, qo = lane >> 4;
  const float* src = x + (((size_t)(g * 16u + m) * 512u + l) * 512u + kk * 32u + qo * 8u);
  float4 a  = ((const float4*)src)[0];
  float4 b2 = ((const float4*)src)[1];
  short8 v;
  v[0] = (short)f2bf(a.x);  v[1] = (short)f2bf(a.y);
  v[2] = (short)f2bf(a.z);  v[3] = (short)f2bf(a.w);
  v[4] = (short)f2bf(b2.x); v[5] = (short)f2bf(b2.y);
  v[6] = (short)f2bf(b2.z); v[7] = (short)f2bf(b2.w);
  *(short8*)(xbf + (size_t)tid * 8u) = v;
}

// Persistent recurrent kernel, 8 fat blocks/group + wave specialization.
// Block b: g = b&3, chunk c = b>>2 (0..7) owns h-slice [c*64, c*64+64) for
// all 4 gates (16 output tiles of 16seq x 16row). 16 waves: x-waves (w<8)
// compute the x_t part (W_now frags in regs, xa from xbf) while s-waves
// (w>=8) poll the 8 arrival flags and ingest the 16 KB short-state into
// LDS; after barrier B1 the s-waves run the recurrent MFMAs (W_short frags
// in regs). Partials land in gl (x) + gl2 (recurrent); after B2 all 1024
// threads do the elementwise update (1 elem each: seq = wave, h = lane).
// Transport identical to round 0/6 (sc1 state + sc1 flags) -- only the
// participant count (32->8) and per-step redundancy (4x) change.
__global__ __launch_bounds__(1024, 1) void lstm_persist(
    const float* __restrict__ Wfp, const float* __restrict__ bfp,
    const float* __restrict__ Wip, const float* __restrict__ bip,
    const float* __restrict__ Wop, const float* __restrict__ bop,
    const float* __restrict__ Whp, const float* __restrict__ bhp,
    const short* __restrict__ xbf,
    short* __restrict__ sbuf,        // [2][4][16kk][64lane][8] bf16 (A-swizzled)
    u32* __restrict__ arrive,        // [4][8]: steps completed by chunk
    float* __restrict__ out)         // [64][512][512] fp32
{
  __shared__ float gl [4 * 16 * 65];  // x-part:       [gate][seq][h(+pad)]
  __shared__ float gl2[4 * 16 * 65];  // recurrent:    [gate][seq][h(+pad)]
  __shared__ short ss[16 * 64 * 8];   // staged state: [kk][lane][8] bf16

  const unsigned b = blockIdx.x;
  const unsigned g = b & 3u;
  const unsigned c = b >> 2;          // 0..7
  const unsigned t = threadIdx.x;     // 0..1023
  const unsigned w = t >> 6;          // 0..15
  const unsigned lane = t & 63u;
  const unsigned m_ = lane & 15u, qo = lane >> 4;
  const int is_x = (w < 8u);
  const unsigned ws = w & 7u;         // role-local wave id
  const unsigned gt = ws >> 1;        // gate type for this wave's 2 tiles
  const unsigned rb0 = (ws & 1u) * 2u; // row-blocks rb0, rb0+1 (16 rows each)

  const float* Wsrc = (gt == 0) ? Wfp : (gt == 1) ? Wip : (gt == 2) ? Wop : Whp;
  const float* bsrc = (gt == 0) ? bfp : (gt == 1) ? bip : (gt == 2) ? bop : bhp;

  // ---- one-time: 2 tiles of B-fragments (W rows c*64 + rb*16 + [0,16)).
  // x-waves take W_now (cols [512,1024)), s-waves W_short (cols [0,512)).
  // B[k][n]: n = lane&15 (gate row), k = kk*32 + qo*8 + j.
  short8 wf[2][16];
  float bias[2];
#pragma unroll
  for (int ti = 0; ti < 2; ti++) {
    unsigned row = c * 64u + (rb0 + (unsigned)ti) * 16u + m_;
    const float* wrow = Wsrc + (size_t)row * 1024u + qo * 8u + (is_x ? 512u : 0u);
#pragma unroll
    for (int kk = 0; kk < 16; kk++) {
      short8 v;
#pragma unroll
      for (int j = 0; j < 8; j++) v[j] = (short)f2bf(wrow[kk * 32 + j]);
      wf[ti][kk] = v;
    }
    bias[ti] = is_x ? bsrc[row] : 0.f;
  }

  // elementwise ownership: thread t <-> (seq = w, hloc = lane)
  const unsigned seq = w;
  float longv = 0.f;
  float* outp = out + (size_t)(g * 16u + seq) * (512u * 512u) + (c * 64u + lane);

  // sbuf store slot (u32 = 2 adjacent bf16), even lanes only. Writer puts
  // state elem (seq, k=c*64+hloc) where the A-frag reader expects it:
  // kk2 = k>>5, lane_s = ((k>>3)&3)*16 + seq, jj = k&7.
  u32* sdst;
  {
    unsigned k   = c * 64u + lane;     // lane even for storing threads
    unsigned kk2 = k >> 5;
    unsigned ls  = ((k >> 3) & 3u) * 16u + seq;
    unsigned jj  = k & 7u;
    sdst = (u32*)sbuf + ((((size_t)g) * 16u + kk2) * 64u + ls) * 4u + (jj >> 1);
  }
  const size_t sslot = (size_t)4u * 16u * 64u * 4u;  // u32s per buffer slot

  const u32* fl = arrive + g * 8u;

  for (int l = 0; l < NSTEPS; l++) {
    // ================= phase 1 (concurrent roles) =================
    if (is_x) {
      // x-part: independent of peers; overlaps the s-waves' flag wait.
      const short8* xt = (const short8*)xbf + ((size_t)(l * 4 + g) * 16u) * 64u + lane;
      float4v a0[4], a1[4];
      {
        float4v b0 = {bias[0], bias[0], bias[0], bias[0]};
        float4v b1 = {bias[1], bias[1], bias[1], bias[1]};
        float4v zz = {0.f, 0.f, 0.f, 0.f};
        a0[0] = b0; a0[1] = zz; a0[2] = zz; a0[3] = zz;
        a1[0] = b1; a1[1] = zz; a1[2] = zz; a1[3] = zz;
      }
#pragma unroll
      for (int kk = 0; kk < 16; kk++) {
        short8 sa = xt[(size_t)kk * 64u];
        a0[kk & 3] = __builtin_amdgcn_mfma_f32_16x16x32_bf16(sa, wf[0][kk], a0[kk & 3], 0, 0, 0);
        a1[kk & 3] = __builtin_amdgcn_mfma_f32_16x16x32_bf16(sa, wf[1][kk], a1[kk & 3], 0, 0, 0);
      }
      float4v t0 = (a0[0] + a0[1]) + (a0[2] + a0[3]);
      float4v t1 = (a1[0] + a1[1]) + (a1[2] + a1[3]);
      // C/D: col = lane&15 -> gate row, row = qo*4+r -> seq
#pragma unroll
      for (int r = 0; r < 4; r++) {
        gl[(gt * 16u + qo * 4u + (unsigned)r) * 65u + (rb0 + 0u) * 16u + m_] = t0[r];
        gl[(gt * 16u + qo * 4u + (unsigned)r) * 65u + (rb0 + 1u) * 16u + m_] = t1[r];
      }
    } else if (l > 0) {
      // s-waves: wait for all 8 chunks to post step l-1 (1 flag line).
      if (lane < 8u) {
        long spins = 0;
        while (__hip_atomic_load(fl + lane, __ATOMIC_RELAXED,
                                 __HIP_MEMORY_SCOPE_AGENT) < (u32)l) {
          __builtin_amdgcn_s_sleep(1);
          if (++spins > (100LL * 1000 * 1000)) break;  // bail -> wrong, not hung
        }
      }
      // ingest rows kk = 2*ws, 2*ws+1 (sc1 coherent u64 loads) -> LDS
      const u64* stM = (const u64*)sbuf +
                       ((size_t)(((unsigned)(l - 1) & 1u) * 4u + g) * 16u) * 128u +
                       (size_t)lane * 2u;
      U64x2 r0, r1;
      {
        unsigned k0 = 2u * ws, k1 = 2u * ws + 1u;
        r0.x = __hip_atomic_load(stM + (size_t)k0 * 128u,      __ATOMIC_RELAXED, __HIP_MEMORY_SCOPE_AGENT);
        r0.y = __hip_atomic_load(stM + (size_t)k0 * 128u + 1u, __ATOMIC_RELAXED, __HIP_MEMORY_SCOPE_AGENT);
        r1.x = __hip_atomic_load(stM + (size_t)k1 * 128u,      __ATOMIC_RELAXED, __HIP_MEMORY_SCOPE_AGENT);
        r1.y = __hip_atomic_load(stM + (size_t)k1 * 128u + 1u, __ATOMIC_RELAXED, __HIP_MEMORY_SCOPE_AGENT);
        *(short8*)(ss + k0 * 512u + lane * 8u) = __builtin_bit_cast(short8, r0);
        *(short8*)(ss + k1 * 512u + lane * 8u) = __builtin_bit_cast(short8, r1);
      }
    }
    __syncthreads();   // B1: ss staged, gl written

    // ================= phase 2 (s-waves compute recurrent part) ==========
    if (!is_x) {
      float4v a0[4], a1[4];
      {
        float4v zz = {0.f, 0.f, 0.f, 0.f};
#pragma unroll
        for (int q = 0; q < 4; q++) { a0[q] = zz; a1[q] = zz; }
      }
      if (l > 0) {
#pragma unroll
        for (int kk = 0; kk < 16; kk++) {
          short8 sa = *(const short8*)(ss + (unsigned)kk * 512u + lane * 8u);
          a0[kk & 3] = __builtin_amdgcn_mfma_f32_16x16x32_bf16(sa, wf[0][kk], a0[kk & 3], 0, 0, 0);
          a1[kk & 3] = __builtin_amdgcn_mfma_f32_16x16x32_bf16(sa, wf[1][kk], a1[kk & 3], 0, 0, 0);
        }
      }
      float4v t0 = (a0[0] + a0[1]) + (a0[2] + a0[3]);
      float4v t1 = (a1[0] + a1[1]) + (a1[2] + a1[3]);
#pragma unroll
      for (int r = 0; r < 4; r++) {
        gl2[(gt * 16u + qo * 4u + (unsigned)r) * 65u + (rb0 + 0u) * 16u + m_] = t0[r];
        gl2[(gt * 16u + qo * 4u + (unsigned)r) * 65u + (rb0 + 1u) * 16u + m_] = t1[r];
      }
    }
    __syncthreads();   // B2: gl2 written

    // ================= phase 3 (all 1024 threads: elementwise) ===========
    float fg = gl[(0u * 16u + seq) * 65u + lane] + gl2[(0u * 16u + seq) * 65u + lane];
    float ig = gl[(1u * 16u + seq) * 65u + lane] + gl2[(1u * 16u + seq) * 65u + lane];
    float og = gl[(2u * 16u + seq) * 65u + lane] + gl2[(2u * 16u + seq) * 65u + lane];
    float hg = gl[(3u * 16u + seq) * 65u + lane] + gl2[(3u * 16u + seq) * 65u + lane];
    fg = 1.f / (1.f + __expf(-fg));
    ig = 1.f / (1.f + __expf(-ig));
    og = 1.f / (1.f + __expf(-og));
    longv = fg * longv + ig * hg;                 // no activation on h (ref)
    float e  = __expf(-2.f * fabsf(longv));
    float th = (1.f - e) / (1.f + e);
    th = (longv < 0.f) ? -th : th;
    float sh = og * th;

    // pack adjacent-h pair into u32, even lanes store coherently (sc1)
    unsigned short mybf = f2bf(sh);
    float shn = __shfl_xor(sh, 1);
    if ((lane & 1u) == 0u) {
      u32 val = (u32)mybf | ((u32)f2bf(shn) << 16);
      __hip_atomic_store(sdst + ((size_t)((unsigned)l & 1u)) * sslot, val,
                         __ATOMIC_RELAXED, __HIP_MEMORY_SCOPE_AGENT);
    }
    // per-thread data-store ack before the barrier; then flag post.
    asm volatile("s_waitcnt vmcnt(0)" ::: "memory");
    __syncthreads();   // B3: all block stores acked at coherence point
    if (t == 0)
      __hip_atomic_store((u32*)(arrive + g * 8u + c), (u32)(l + 1),
                         __ATOMIC_RELAXED, __HIP_MEMORY_SCOPE_AGENT);

    // output store AFTER the flag post: keeps it off the sync critical path
    outp[(size_t)l * 512u] = sh;
  }
}

extern "C" void kernel_launch(void* const* d_in, const int* in_sizes, int n_in,
                              void* d_out, int out_size, void* d_ws, size_t ws_size,
                              hipStream_t stream) {
  const float* x   = (const float*)d_in[0];
  const float* Wf  = (const float*)d_in[1];
  const float* bfv = (const float*)d_in[2];
  const float* Wi  = (const float*)d_in[3];
  const float* biv = (const float*)d_in[4];
  const float* Wo  = (const float*)d_in[5];
  const float* bov = (const float*)d_in[6];
  const float* Wh  = (const float*)d_in[7];
  const float* bhv = (const float*)d_in[8];
  float* out = (float*)d_out;

  char* ws = (char*)d_ws;
  short* xbf    = (short*)ws;                                // 33,554,432 B
  short* sbuf   = (short*)(ws + 33554432);                   //    131,072 B
  u32*   arrive = (u32*)(ws + 33554432 + 131072);            //        512 B

  // zero the arrival counters (sbuf needs no init: slot for step l is fully
  // written before anyone reads it; step 0 has no recurrent read)
  hipMemsetAsync(ws + 33554432 + 131072, 0, 512, stream);

  xprep_kernel<<<8192, 256, 0, stream>>>(x, xbf);

  lstm_persist<<<32, 1024, 0, stream>>>(Wf, bfv, Wi, biv, Wo, bov, Wh, bhv,
                                        xbf, sbuf, arrive, out);
}